// Round 10
// baseline (42.600 us; speedup 1.0000x reference)
//
#include <hip/hip_runtime.h>

#define DIM 128
#define NGRAPH 4096
#define NSTEM 81920
#define NJROW 81920
#define NOUT 105
#define COLS 2111           // 1 stop + 10 break + 2100 add
#define SPG 20              // stems per graph
#define ROWS 64
#define XPAD 136            // shorts: 272B row stride (conflict-free A-frag b128)
#define TT 4                // tiles per block
#define NBSB 320            // stem blocks  (320*4*64 = 81920 rows)
#define NBJB 320            // jbond blocks
#define NSCB 16             // scalar-copy blocks (16*256 = 4096 graphs)

typedef __attribute__((ext_vector_type(8))) short bf16x8;
typedef __attribute__((ext_vector_type(4))) float f32x4;

// HW packed f32->bf16 RNE
__device__ __forceinline__ unsigned int cvtpk(float lo, float hi) {
    unsigned int r;
    asm("v_cvt_pk_bf16_f32 %0, %1, %2" : "=v"(r) : "v"(lo), "v"(hi));
    return r;
}
__device__ __forceinline__ float lrelu(float v) { return v > 0.f ? v : 0.01f * v; }

__device__ __forceinline__ void lgkm_barrier() {
    asm volatile("s_waitcnt lgkmcnt(0)" ::: "memory");
    __builtin_amdgcn_s_barrier();
}

__device__ __forceinline__ void issue_gather(const float* __restrict__ atom,
                                             const int (&a)[4], int ko, float4 (&g)[8])
{
    #pragma unroll
    for (int q = 0; q < 4; ++q) {
        g[2*q]   = *(const float4*)(atom + a[q] * DIM + ko);
        g[2*q+1] = *(const float4*)(atom + a[q] * DIM + ko + 4);
    }
}

__device__ __forceinline__ void stage_lds(short (*X)[XPAD], int rb, int ko,
                                          const float4 (&g)[8])
{
    #pragma unroll
    for (int q = 0; q < 4; ++q) {
        uint4 p;
        p.x = cvtpk(g[2*q].x,   g[2*q].y);
        p.y = cvtpk(g[2*q].z,   g[2*q].w);
        p.z = cvtpk(g[2*q+1].x, g[2*q+1].y);
        p.w = cvtpk(g[2*q+1].z, g[2*q+1].w);
        *(uint4*)&X[q * 16 + rb][ko] = p;
    }
}

// fragment self-pack: element i of lane l = W[(kt*32 + (l>>4)*8 + i)*stride + col]
__device__ __forceinline__ bf16x8 pack_frag(const float* __restrict__ W,
                                            int kt, int lq, int stride, int col)
{
    float e[8];
    #pragma unroll
    for (int i = 0; i < 8; ++i)
        e[i] = W[(kt * 32 + lq * 8 + i) * stride + col];
    uint4 p;
    p.x = cvtpk(e[0], e[1]); p.y = cvtpk(e[2], e[3]);
    p.z = cvtpk(e[4], e[5]); p.w = cvtpk(e[6], e[7]);
    return __builtin_bit_cast(bf16x8, p);
}

// ---- single kernel: stem blocks | jbond blocks | scalar-copy blocks.
// Self-packed weights (no prep kernel), 2-buffer LDS with H written in-place,
// depth-1 rolling gather prefetch, lgkm-only barriers, non-temporal output.
__global__ __launch_bounds__(256, 3) void fused_all(
    const float* __restrict__ atom,
    const int* __restrict__ sidx, const int* __restrict__ jidx,
    const float* __restrict__ W1s, const float* __restrict__ b1s,
    const float* __restrict__ W2s, const float* __restrict__ b2s,
    const float* __restrict__ W1j, const float* __restrict__ b1j,
    const float* __restrict__ W2j, const float* __restrict__ b2j,
    const float* __restrict__ so, float* __restrict__ out)
{
    __shared__ short Xbuf[2][ROWS][XPAD];
    __shared__ float red[4][ROWS];
    const int bid = blockIdx.x;
    const int tid = threadIdx.x;

    if (bid >= NBSB + NBJB) {          // scalar copy: value + stop logit
        int gph = (bid - NBSB - NBJB) * 256 + tid;
        float2 v = *(const float2*)(so + 2 * gph);
        __builtin_nontemporal_store(v.x, &out[gph]);
        __builtin_nontemporal_store(v.y, &out[NGRAPH + gph * COLS]);
        return;
    }

    const bool isStem = bid < NBSB;
    const int pb = isStem ? bid : bid - NBSB;
    const int w = tid >> 6, l = tid & 63;
    const int lq = l >> 4, lc = l & 15;
    const int rb = tid >> 4, ko = (tid & 15) * 8;

    const int*   idx = isStem ? sidx : jidx;
    const float* b1  = isStem ? b1s : b1j;
    const int tbase = pb * TT * ROWS;

    // (1) indices, (2) tile-0 gather: longest-latency loads issue first
    int a[TT][4];
    #pragma unroll
    for (int t = 0; t < TT; ++t)
        #pragma unroll
        for (int q = 0; q < 4; ++q)
            a[t][q] = idx[tbase + t * ROWS + q * 16 + rb];

    float4 g[8];
    issue_gather(atom, a[0], ko, g);

    // (3) weight fragments self-packed from raw f32 (L2-hot broadcast reads,
    // complete under the gather's latency)
    const float* Wsrc1 = isStem ? W1s : W1j;
    bf16x8 wf1[4][2];
    #pragma unroll
    for (int kt = 0; kt < 4; ++kt)
        #pragma unroll
        for (int j = 0; j < 2; ++j)
            wf1[kt][j] = pack_frag(Wsrc1, kt, lq, DIM, (w * 2 + j) * 16 + lc);

    // L1 swapped layout: lane's 4 acc entries = channels c0..c0+3
    float4 bb1[2];
    #pragma unroll
    for (int j = 0; j < 2; ++j)
        bb1[j] = *(const float4*)(b1 + (w * 2 + j) * 16 + lq * 4);

    bf16x8 wf2[4][2];
    float bb2[2];
    float4 wvj[2];
    float bj = 0.f;
    if (isStem) {
        #pragma unroll
        for (int kt = 0; kt < 4; ++kt)
            #pragma unroll
            for (int j = 0; j < 2; ++j) {
                int c = (w * 2 + j) * 16 + lc;
                int cl = c > 104 ? 104 : c;      // clamp addr; results masked at store
                wf2[kt][j] = pack_frag(W2s, kt, lq, NOUT, cl);
            }
        #pragma unroll
        for (int j = 0; j < 2; ++j) {
            int c = (w * 2 + j) * 16 + lc;
            bb2[j] = (c < NOUT) ? b2s[c] : 0.f;
        }
    } else {
        #pragma unroll
        for (int j = 0; j < 2; ++j)
            wvj[j] = *(const float4*)(W2j + (w * 2 + j) * 16 + lq * 4);
        bj = b2j[0];
    }

    stage_lds(Xbuf[0], rb, ko, g);
    lgkm_barrier();

    if (isStem) {
        #pragma unroll
        for (int t = 0; t < TT; ++t) {
            short (*XA)[XPAD] = Xbuf[t & 1];
            short (*XB)[XPAD] = Xbuf[(t + 1) & 1];
            if (t + 1 < TT) issue_gather(atom, a[t + 1], ko, g);

            // ---- L1 swapped: acc[m][j][rg] = H[s=m*16+lc][c=(w*2+j)*16+lq*4+rg]
            f32x4 acc[4][2];
            #pragma unroll
            for (int j = 0; j < 2; ++j)
                #pragma unroll
                for (int m = 0; m < 4; ++m)
                    acc[m][j] = (f32x4){bb1[j].x, bb1[j].y, bb1[j].z, bb1[j].w};
            #pragma unroll
            for (int kt = 0; kt < 4; ++kt) {
                bf16x8 A0 = *(const bf16x8*)&XA[lc]     [kt * 32 + lq * 8];
                bf16x8 A1 = *(const bf16x8*)&XA[16 + lc][kt * 32 + lq * 8];
                bf16x8 A2 = *(const bf16x8*)&XA[32 + lc][kt * 32 + lq * 8];
                bf16x8 A3 = *(const bf16x8*)&XA[48 + lc][kt * 32 + lq * 8];
                #pragma unroll
                for (int j = 0; j < 2; ++j) {
                    acc[0][j] = __builtin_amdgcn_mfma_f32_16x16x32_bf16(wf1[kt][j], A0, acc[0][j], 0, 0, 0);
                    acc[1][j] = __builtin_amdgcn_mfma_f32_16x16x32_bf16(wf1[kt][j], A1, acc[1][j], 0, 0, 0);
                    acc[2][j] = __builtin_amdgcn_mfma_f32_16x16x32_bf16(wf1[kt][j], A2, acc[2][j], 0, 0, 0);
                    acc[3][j] = __builtin_amdgcn_mfma_f32_16x16x32_bf16(wf1[kt][j], A3, acc[3][j], 0, 0, 0);
                }
            }
            lgkm_barrier();                     // alpha: all waves done reading XA

            // H -> XA in place (2 cvt_pk + 1 b64 write per (m,j))
            #pragma unroll
            for (int m = 0; m < 4; ++m)
                #pragma unroll
                for (int j = 0; j < 2; ++j) {
                    uint2 hp;
                    hp.x = cvtpk(lrelu(acc[m][j][0]), lrelu(acc[m][j][1]));
                    hp.y = cvtpk(lrelu(acc[m][j][2]), lrelu(acc[m][j][3]));
                    *(uint2*)&XA[m * 16 + lc][(w * 2 + j) * 16 + lq * 4] = hp;
                }
            lgkm_barrier();                     // beta1: H visible

            // ---- L2 unswapped: acc2[m][j][rg] = out[s=m*16+lq*4+rg][c=(w*2+j)*16+lc]
            f32x4 acc2[4][2];
            #pragma unroll
            for (int j = 0; j < 2; ++j)
                #pragma unroll
                for (int m = 0; m < 4; ++m)
                    acc2[m][j] = (f32x4){bb2[j], bb2[j], bb2[j], bb2[j]};
            #pragma unroll
            for (int kt = 0; kt < 4; ++kt) {
                bf16x8 A0 = *(const bf16x8*)&XA[lc]     [kt * 32 + lq * 8];
                bf16x8 A1 = *(const bf16x8*)&XA[16 + lc][kt * 32 + lq * 8];
                bf16x8 A2 = *(const bf16x8*)&XA[32 + lc][kt * 32 + lq * 8];
                bf16x8 A3 = *(const bf16x8*)&XA[48 + lc][kt * 32 + lq * 8];
                #pragma unroll
                for (int j = 0; j < 2; ++j) {
                    acc2[0][j] = __builtin_amdgcn_mfma_f32_16x16x32_bf16(A0, wf2[kt][j], acc2[0][j], 0, 0, 0);
                    acc2[1][j] = __builtin_amdgcn_mfma_f32_16x16x32_bf16(A1, wf2[kt][j], acc2[1][j], 0, 0, 0);
                    acc2[2][j] = __builtin_amdgcn_mfma_f32_16x16x32_bf16(A2, wf2[kt][j], acc2[2][j], 0, 0, 0);
                    acc2[3][j] = __builtin_amdgcn_mfma_f32_16x16x32_bf16(A3, wf2[kt][j], acc2[3][j], 0, 0, 0);
                }
            }

            const int baseS = tbase + t * ROWS;
            #pragma unroll
            for (int m = 0; m < 4; ++m)
                #pragma unroll
                for (int rg = 0; rg < 4; ++rg) {
                    int S = baseS + m * 16 + lq * 4 + rg;
                    int gph = S / SPG, sl = S - gph * SPG;
                    float* ob = out + NGRAPH + gph * COLS + 1 + 10 + sl * NOUT;
                    #pragma unroll
                    for (int j = 0; j < 2; ++j) {
                        int c = (w * 2 + j) * 16 + lc;
                        if (c < NOUT) __builtin_nontemporal_store(acc2[m][j][rg], &ob[c]);
                    }
                }

            // stage next X late: full-tile distance from its gather issue
            if (t + 1 < TT) stage_lds(XB, rb, ko, g);
            lgkm_barrier();                     // beta2: XA free, Xnext visible
        }
    } else {
        #pragma unroll
        for (int t = 0; t < TT; ++t) {
            short (*XA)[XPAD] = Xbuf[t & 1];
            short (*XB)[XPAD] = Xbuf[(t + 1) & 1];
            if (t + 1 < TT) issue_gather(atom, a[t + 1], ko, g);

            f32x4 acc[4][2];
            #pragma unroll
            for (int j = 0; j < 2; ++j)
                #pragma unroll
                for (int m = 0; m < 4; ++m)
                    acc[m][j] = (f32x4){bb1[j].x, bb1[j].y, bb1[j].z, bb1[j].w};
            #pragma unroll
            for (int kt = 0; kt < 4; ++kt) {
                bf16x8 A0 = *(const bf16x8*)&XA[lc]     [kt * 32 + lq * 8];
                bf16x8 A1 = *(const bf16x8*)&XA[16 + lc][kt * 32 + lq * 8];
                bf16x8 A2 = *(const bf16x8*)&XA[32 + lc][kt * 32 + lq * 8];
                bf16x8 A3 = *(const bf16x8*)&XA[48 + lc][kt * 32 + lq * 8];
                #pragma unroll
                for (int j = 0; j < 2; ++j) {
                    acc[0][j] = __builtin_amdgcn_mfma_f32_16x16x32_bf16(wf1[kt][j], A0, acc[0][j], 0, 0, 0);
                    acc[1][j] = __builtin_amdgcn_mfma_f32_16x16x32_bf16(wf1[kt][j], A1, acc[1][j], 0, 0, 0);
                    acc[2][j] = __builtin_amdgcn_mfma_f32_16x16x32_bf16(wf1[kt][j], A2, acc[2][j], 0, 0, 0);
                    acc[3][j] = __builtin_amdgcn_mfma_f32_16x16x32_bf16(wf1[kt][j], A3, acc[3][j], 0, 0, 0);
                }
            }

            // dot with W2j over lane's channels, reduce over lq (shfl 16,32)
            float pf[4];
            #pragma unroll
            for (int m = 0; m < 4; ++m) {
                float p = 0.f;
                #pragma unroll
                for (int j = 0; j < 2; ++j) {
                    p += lrelu(acc[m][j][0]) * wvj[j].x;
                    p += lrelu(acc[m][j][1]) * wvj[j].y;
                    p += lrelu(acc[m][j][2]) * wvj[j].z;
                    p += lrelu(acc[m][j][3]) * wvj[j].w;
                }
                pf[m] = p;
            }
            #pragma unroll
            for (int m = 0; m < 4; ++m) {
                pf[m] += __shfl_xor(pf[m], 16, 64);
                pf[m] += __shfl_xor(pf[m], 32, 64);
            }
            if (l < 16)
                #pragma unroll
                for (int m = 0; m < 4; ++m)
                    red[w][m * 16 + l] = pf[m];
            lgkm_barrier();                     // alpha: red visible, XA reads done

            if (tid < 32) {
                int r0 = tid * 2;
                float s0 = red[0][r0] + red[1][r0] + red[2][r0] + red[3][r0];
                float s1 = red[0][r0+1] + red[1][r0+1] + red[2][r0+1] + red[3][r0+1];
                float v = (s0 + s1) * 0.5f + bj;
                int B = (pb * TT + t) * 32 + tid;
                int gg = B / 10, c = B - gg * 10;
                __builtin_nontemporal_store(v, &out[NGRAPH + gg * COLS + 1 + c]);
            }
            if (t + 1 < TT) stage_lds(XB, rb, ko, g);
            lgkm_barrier();                     // beta: Xnext visible, red reads done
        }
    }
}

extern "C" void kernel_launch(void* const* d_in, const int* in_sizes, int n_in,
                              void* d_out, int out_size, void* d_ws, size_t ws_size,
                              hipStream_t stream) {
    const float* per_atom_out = (const float*)d_in[0];
    const float* scalar_outs  = (const float*)d_in[1];
    const int*   stem_atmidx  = (const int*)d_in[2];
    const int*   jbond_atmidx = (const int*)d_in[3];
    const float* W1s = (const float*)d_in[5];
    const float* b1s = (const float*)d_in[6];
    const float* W2s = (const float*)d_in[7];
    const float* b2s = (const float*)d_in[8];
    const float* W1j = (const float*)d_in[9];
    const float* b1j = (const float*)d_in[10];
    const float* W2j = (const float*)d_in[11];
    const float* b2j = (const float*)d_in[12];
    float* out = (float*)d_out;

    hipLaunchKernelGGL(fused_all, dim3(NBSB + NBJB + NSCB), dim3(256), 0, stream,
                       per_atom_out, stem_atmidx, jbond_atmidx,
                       W1s, b1s, W2s, b2s, W1j, b1j, W2j, b2j,
                       scalar_outs, out);
}